// Round 5
// baseline (618.725 us; speedup 1.0000x reference)
//
#include <hip/hip_runtime.h>

// TemporalTX: T=512, B=16, D=128, H=8, DH=128, P=512, J=1024.
// INPUTS fp32; OUTPUT buffer fp32 (reference dtype). Workspace intermediates bf16.
// out = [layer_out (1M) | inputs copy (1M) | layer_out copy (1M)] fp32 elems.

typedef short s16x8 __attribute__((ext_vector_type(8)));
typedef float f32x4 __attribute__((ext_vector_type(4)));

#define MFMA(a, b, c) __builtin_amdgcn_mfma_f32_16x16x32_bf16((a), (b), (c), 0, 0, 0)

__device__ __forceinline__ unsigned short f2b(float f) {
  unsigned int x = __builtin_bit_cast(unsigned int, f);
  x += 0x7fffu + ((x >> 16) & 1u);   // RNE
  return (unsigned short)(x >> 16);
}
__device__ __forceinline__ s16x8 ldg8(const unsigned short* p) {  // bf16 x8 (ws)
  return *(const s16x8*)p;
}
__device__ __forceinline__ s16x8 ldf8(const float* p) {  // fp32 x8 -> bf16 x8
  float4 u = ((const float4*)p)[0];
  float4 v = ((const float4*)p)[1];
  s16x8 r;
  r[0] = (short)f2b(u.x); r[1] = (short)f2b(u.y);
  r[2] = (short)f2b(u.z); r[3] = (short)f2b(u.w);
  r[4] = (short)f2b(v.x); r[5] = (short)f2b(v.y);
  r[6] = (short)f2b(v.z); r[7] = (short)f2b(v.w);
  return r;
}

// ---------------------------------------------------------------------------
// KV projection over xm = cat(mem0, x):  kv[j][b][f] = sum_e xm[j][b][e]*wkv[f][e]
// f<1024 -> K[b][h][j][d];  f>=1024 -> Vt[b][h][d][j] (transpose via LDS+barrier)
__global__ __launch_bounds__(256, 2) void k_gemm_kv(
    const float* __restrict__ x, const float* __restrict__ mem,
    const float* __restrict__ wkv,
    unsigned short* __restrict__ Kk, unsigned short* __restrict__ Vt) {
  __shared__ float tbuf[4][16][128];
  const int lane = threadIdx.x & 63;
  const int w = threadIdx.x >> 6;
  const int wid = blockIdx.x * 4 + w;  // 0..16383
  const int nc = wid & 15;
  const int b = (wid >> 4) & 15;
  const int j0 = (wid >> 8) * 16;  // 0..1008
  const int l15 = lane & 15, l4 = lane >> 4;

  const int jr = j0 + l15;
  const float* arow =
      (jr < 512 ? mem + (jr * 16 + b) * 128 : x + ((jr - 512) * 16 + b) * 128) + l4 * 8;
  s16x8 a0 = ldf8(arow), a1 = ldf8(arow + 32), a2 = ldf8(arow + 64), a3 = ldf8(arow + 96);

  f32x4 acc[8] = {};
#pragma unroll
  for (int fc = 0; fc < 8; ++fc) {
    const float* brow = wkv + (nc * 128 + fc * 16 + l15) * 128 + l4 * 8;
    acc[fc] = MFMA(a0, ldf8(brow), acc[fc]);
    acc[fc] = MFMA(a1, ldf8(brow + 32), acc[fc]);
    acc[fc] = MFMA(a2, ldf8(brow + 64), acc[fc]);
    acc[fc] = MFMA(a3, ldf8(brow + 96), acc[fc]);
  }

  if (nc >= 8) {  // V waves stage D-frags into LDS for transpose
#pragma unroll
    for (int fc = 0; fc < 8; ++fc)
#pragma unroll
      for (int r = 0; r < 4; ++r) tbuf[w][l4 * 4 + r][fc * 16 + l15] = acc[fc][r];
  }
  __syncthreads();  // uniform: all waves reach this exactly once
  if (nc < 8) {  // K part, h = nc
#pragma unroll
    for (int fc = 0; fc < 8; ++fc)
#pragma unroll
      for (int r = 0; r < 4; ++r) {
        int j = j0 + l4 * 4 + r;
        Kk[((b * 8 + nc) * 1024 + j) * 128 + fc * 16 + l15] = f2b(acc[fc][r]);
      }
  } else {  // V part, h = nc-8: read transposed (16j x 128d -> d rows, j contig)
    const int h = nc - 8;
#pragma unroll
    for (int half = 0; half < 2; ++half) {
      int dd = half * 64 + lane;
      unsigned int wd[8];
#pragma unroll
      for (int pw = 0; pw < 8; ++pw) {
        unsigned int lo = f2b(tbuf[w][2 * pw][dd]);
        unsigned int hi = f2b(tbuf[w][2 * pw + 1][dd]);
        wd[pw] = lo | (hi << 16);
      }
      unsigned short* dst = Vt + ((b * 8 + h) * 128 + dd) * 1024 + j0;
      ((uint4*)dst)[0] = make_uint4(wd[0], wd[1], wd[2], wd[3]);
      ((uint4*)dst)[1] = make_uint4(wd[4], wd[5], wd[6], wd[7]);
    }
  }
}

// ---------------------------------------------------------------------------
// P projection: P[h][c][d] = sum_e pe[c][e] * wp[h*128+d][e], pe analytic.
__global__ __launch_bounds__(256, 2) void k_gemm_p(
    const float* __restrict__ wp, unsigned short* __restrict__ Pp) {
  const int lane = threadIdx.x & 63;
  const int wid = blockIdx.x * 4 + (threadIdx.x >> 6);  // 0..511
  const int nc = wid & 7;
  const int c0 = (wid >> 3) * 16;
  const int l15 = lane & 15, l4 = lane >> 4;

  const float pos = (float)(1023 - (c0 + l15));
  s16x8 a[4];
#pragma unroll
  for (int ks = 0; ks < 4; ++ks)
#pragma unroll
    for (int jj = 0; jj < 8; ++jj) {
      int e = ks * 32 + l4 * 8 + jj;
      int t = e & 63;
      float ang = pos * exp2f(-0.20762050593046014f * (float)t);  // 10000^(-t/64)
      float val = (e < 64) ? sinf(ang) : cosf(ang);
      a[ks][jj] = (short)f2b(val);
    }

  f32x4 acc[8] = {};
#pragma unroll
  for (int fc = 0; fc < 8; ++fc) {
    const float* brow = wp + (nc * 128 + fc * 16 + l15) * 128 + l4 * 8;
    acc[fc] = MFMA(a[0], ldf8(brow), acc[fc]);
    acc[fc] = MFMA(a[1], ldf8(brow + 32), acc[fc]);
    acc[fc] = MFMA(a[2], ldf8(brow + 64), acc[fc]);
    acc[fc] = MFMA(a[3], ldf8(brow + 96), acc[fc]);
  }
#pragma unroll
  for (int fc = 0; fc < 8; ++fc)
#pragma unroll
    for (int r = 0; r < 4; ++r)
      Pp[(nc * 1024 + c0 + l4 * 4 + r) * 128 + fc * 16 + l15] = f2b(acc[fc][r]);
}

// ---------------------------------------------------------------------------
// Flash attention with TXL relative position, Q-projection fused in prologue.
// One wave = 16 q-rows of one (b,h). All LDS phases fenced by __syncthreads()
// (trip counts block-uniform; extra tiles fully masked => contribute ~0).
__global__ __launch_bounds__(256, 2) void k_flash(
    const float* __restrict__ x, const float* __restrict__ wq,
    const unsigned short* __restrict__ Kk, const unsigned short* __restrict__ Vt,
    const unsigned short* __restrict__ Pp,
    const float* __restrict__ uu, const float* __restrict__ vv,
    unsigned short* __restrict__ OA) {
  __shared__ __align__(16) unsigned short qub[4][16][136];  // 2-way bank stride
  __shared__ __align__(16) unsigned short qvb[4][16][136];
  __shared__ __align__(16) unsigned short pbuf[4][16][72];
  __shared__ float band[4][16][84];  // rel-pos band, cc in [0,79)
  const int lane = threadIdx.x & 63;
  const int w = threadIdx.x >> 6;
  const int bh = blockIdx.x & 127;   // same bh across grp -> L2 locality
  const int grp = blockIdx.x >> 7;   // 0..7
  const int iw = grp * 64 + w * 16;  // 16-row q tile base
  const int b = bh >> 3, h = bh & 7;
  const int l15 = lane & 15, l4 = lane >> 4;
  const float CSCALE = 0.08838834764831845f * 1.4426950408889634f;  // 1/sqrt(128)*log2e

  const unsigned short* K_b = Kk + bh * (1024 * 128);
  const unsigned short* V_b = Vt + bh * (128 * 1024);
  const unsigned short* P_h = Pp + h * (1024 * 128);

  // ---- fused Q projection: q[iw+m][d] = sum_e x[iw+m][b][e] * wq[h*128+d][e]
  s16x8 qu[4], qv[4];
  {
    const float* arow = x + ((iw + l15) * 16 + b) * 128 + l4 * 8;
    s16x8 a0 = ldf8(arow), a1 = ldf8(arow + 32), a2 = ldf8(arow + 64), a3 = ldf8(arow + 96);
    f32x4 qd[8] = {};
#pragma unroll
    for (int fc = 0; fc < 8; ++fc) {
      const float* brow = wq + (h * 128 + fc * 16 + l15) * 128 + l4 * 8;
      qd[fc] = MFMA(a0, ldf8(brow), qd[fc]);
      qd[fc] = MFMA(a1, ldf8(brow + 32), qd[fc]);
      qd[fc] = MFMA(a2, ldf8(brow + 64), qd[fc]);
      qd[fc] = MFMA(a3, ldf8(brow + 96), qd[fc]);
    }
    // D-layout -> LDS (row m=l4*4+r, col d=fc*16+l15), u/v biases folded
#pragma unroll
    for (int fc = 0; fc < 8; ++fc) {
      float ud = uu[h * 128 + fc * 16 + l15];
      float vd = vv[h * 128 + fc * 16 + l15];
#pragma unroll
      for (int r = 0; r < 4; ++r) {
        qub[w][l4 * 4 + r][fc * 16 + l15] = f2b(qd[fc][r] + ud);
        qvb[w][l4 * 4 + r][fc * 16 + l15] = f2b(qd[fc][r] + vd);
      }
    }
    __syncthreads();
#pragma unroll
    for (int ks = 0; ks < 4; ++ks) {
      qu[ks] = *(const s16x8*)&qub[w][l15][ks * 32 + l4 * 8];
      qv[ks] = *(const s16x8*)&qvb[w][l15][ks * 32 + l4 * 8];
    }
  }

  f32x4 O[8] = {};
  float mrow[4], lrow[4];
#pragma unroll
  for (int r = 0; r < 4; ++r) { mrow[r] = -1e4f; lrow[r] = 0.f; }

  // block-uniform trip count (max over the block's waves); extra tiles masked
  const int tmax = (grp * 64 + 48 + 591) >> 6;
  for (int t = 0; t < tmax; ++t) {
    const int j0 = t * 64;
    const int c0 = j0 - iw + 496;  // band: c = j-i+511; local cc = jj-li+15 in [0,78]

    f32x4 sc[4] = {};
#pragma unroll
    for (int fc = 0; fc < 4; ++fc) {
      const unsigned short* kr = K_b + (j0 + fc * 16 + l15) * 128 + l4 * 8;
#pragma unroll
      for (int ks = 0; ks < 4; ++ks) sc[fc] = MFMA(qu[ks], ldg8(kr + ks * 32), sc[fc]);
    }
    f32x4 sp[5] = {};
#pragma unroll
    for (int pc = 0; pc < 5; ++pc) {
      int c = c0 + pc * 16 + l15;
      c = (c > 1023) ? 1023 : c;  // clamped rows feed only masked elements
      const unsigned short* pr = P_h + c * 128 + l4 * 8;
#pragma unroll
      for (int ks = 0; ks < 4; ++ks) sp[pc] = MFMA(qv[ks], ldg8(pr + ks * 32), sp[pc]);
    }
    // stage band (D-layout: row=l4*4+r, bandcol=pc*16+l15)
#pragma unroll
    for (int pc = 0; pc < 5; ++pc)
#pragma unroll
      for (int r = 0; r < 4; ++r) band[w][l4 * 4 + r][pc * 16 + l15] = sp[pc][r];
    __syncthreads();

    // combine content + diagonal band, mask, scale
    float mt[4] = {-1e4f, -1e4f, -1e4f, -1e4f};
#pragma unroll
    for (int fc = 0; fc < 4; ++fc)
#pragma unroll
      for (int r = 0; r < 4; ++r) {
        int li = l4 * 4 + r;
        int jj = fc * 16 + l15;
        float pv = band[w][li][jj - li + 15];
        float logit = (sc[fc][r] + pv) * CSCALE;
        if (j0 + jj > iw + li + 512) logit = -60.0f;  // masked (exp2 ~ 1e-18)
        sc[fc][r] = logit;
        mt[r] = fmaxf(mt[r], logit);
      }

    float alpha[4];
#pragma unroll
    for (int r = 0; r < 4; ++r) {
      float m = mt[r];
#pragma unroll
      for (int off = 1; off < 16; off <<= 1) m = fmaxf(m, __shfl_xor(m, off, 64));
      float mn = fmaxf(mrow[r], m);
      alpha[r] = exp2f(mrow[r] - mn);
      mrow[r] = mn;
    }

    float rs[4] = {0.f, 0.f, 0.f, 0.f};
#pragma unroll
    for (int fc = 0; fc < 4; ++fc)
#pragma unroll
      for (int r = 0; r < 4; ++r) {
        float p = exp2f(sc[fc][r] - mrow[r]);
        rs[r] += p;
        pbuf[w][l4 * 4 + r][fc * 16 + l15] = f2b(p);
      }
#pragma unroll
    for (int r = 0; r < 4; ++r) {
      float s = rs[r];
#pragma unroll
      for (int off = 1; off < 16; off <<= 1) s += __shfl_xor(s, off, 64);
      lrow[r] = lrow[r] * alpha[r] + s;
    }
#pragma unroll
    for (int fd = 0; fd < 8; ++fd)
#pragma unroll
      for (int r = 0; r < 4; ++r) O[fd][r] *= alpha[r];

    __syncthreads();  // probs visible before A-layout read
    const unsigned short* pb = &pbuf[w][l15][0];
    s16x8 pa0 = *(const s16x8*)(pb + l4 * 8);
    s16x8 pa1 = *(const s16x8*)(pb + 32 + l4 * 8);
#pragma unroll
    for (int fd = 0; fd < 8; ++fd) {
      const unsigned short* vr = V_b + (fd * 16 + l15) * 1024 + j0 + l4 * 8;
      O[fd] = MFMA(pa0, ldg8(vr), O[fd]);
      O[fd] = MFMA(pa1, ldg8(vr + 32), O[fd]);
    }
    __syncthreads();  // protect band/pbuf WAR before next iteration
  }

  // epilogue: O/l -> OA[i][b][h*128+d]
#pragma unroll
  for (int fd = 0; fd < 8; ++fd)
#pragma unroll
    for (int r = 0; r < 4; ++r) {
      int li = l4 * 4 + r;
      float o = O[fd][r] / fmaxf(lrow[r], 1e-30f);
      OA[((iw + li) * 16 + b) * 1024 + h * 128 + fd * 16 + l15] = f2b(o);
    }
}

// ---------------------------------------------------------------------------
// Output projection: out[i][b][e] = sum_f OA[i][b][f] * wout[e][f], K=1024.
// fp32 OUTPUT: layer_out -> out[0] and out[2M]; raw fp32 inputs -> out[1M].
__global__ __launch_bounds__(256, 2) void k_out(
    const unsigned short* __restrict__ OA, const float* __restrict__ wout,
    const float* __restrict__ x, float* __restrict__ out) {
  const int lane = threadIdx.x & 63;
  const int wid = blockIdx.x * 4 + (threadIdx.x >> 6);  // 0..1023
  const int half = wid & 1;
  const int rt = wid >> 1;  // i in 0..511
  const int l15 = lane & 15, l4 = lane >> 4;

  f32x4 acc[4] = {};
  const unsigned short* arow = OA + (rt * 16 + l15) * 1024 + l4 * 8;
#pragma unroll 4
  for (int ks = 0; ks < 32; ++ks) {
    s16x8 a = ldg8(arow + ks * 32);
#pragma unroll
    for (int fc = 0; fc < 4; ++fc) {
      const float* brow = wout + (half * 64 + fc * 16 + l15) * 1024 + ks * 32 + l4 * 8;
      acc[fc] = MFMA(a, ldf8(brow), acc[fc]);
    }
  }
#pragma unroll
  for (int fc = 0; fc < 4; ++fc)
#pragma unroll
    for (int r = 0; r < 4; ++r) {
      int rg = rt * 16 + l4 * 4 + r;
      int e = half * 64 + fc * 16 + l15;
      float v = acc[fc][r];
      out[rg * 128 + e] = v;
      out[2097152 + rg * 128 + e] = v;
    }
  // copy inputs (fp32) -> out1 (fp32, exact), 1024 floats per wave-chunk
  const float4* src = (const float4*)(x + rt * 2048 + half * 1024);
  float4* dst = (float4*)(out + 1048576 + rt * 2048 + half * 1024);
  dst[lane] = src[lane];
  dst[64 + lane] = src[64 + lane];
  dst[128 + lane] = src[128 + lane];
  dst[192 + lane] = src[192 + lane];
}

// ---------------------------------------------------------------------------
extern "C" void kernel_launch(void* const* d_in, const int* in_sizes, int n_in,
                              void* d_out, int out_size, void* d_ws, size_t ws_size,
                              hipStream_t stream) {
  (void)in_sizes; (void)n_in; (void)out_size; (void)ws_size;
  const float* x    = (const float*)d_in[0];  // [512][16][128] fp32
  const float* mem  = (const float*)d_in[1];  // [2][512][16][128] fp32
  const float* wkv  = (const float*)d_in[2];  // [2048][128] fp32
  const float* wq   = (const float*)d_in[3];  // [1024][128] fp32
  const float* wp   = (const float*)d_in[4];  // [1024][128] fp32
  const float* wout = (const float*)d_in[5];  // [128][1024] fp32
  const float* uu   = (const float*)d_in[6];  // [8][128] fp32
  const float* vv   = (const float*)d_in[7];  // [8][128] fp32
  float* out = (float*)d_out;                 // fp32, 3,145,728 elems
  unsigned short* ws = (unsigned short*)d_ws;

  unsigned short* Kk = ws;             // [16][8][1024][128] 16,777,216
  unsigned short* Vt = ws + 16777216;  // [16][8][128][1024] 16,777,216
  unsigned short* Pp = ws + 33554432;  // [8][1024][128]      1,048,576
  unsigned short* OA = ws + 34603008;  // [512][16][1024]     8,388,608
  // total ws: 42,991,616 bf16 elems = ~82 MB

  k_gemm_kv<<<4096, 256, 0, stream>>>(x, mem, wkv, Kk, Vt);
  k_gemm_p<<<128, 256, 0, stream>>>(wp, Pp);
  k_flash<<<1024, 256, 0, stream>>>(x, wq, Kk, Vt, Pp, uu, vv, OA);
  k_out<<<256, 256, 0, stream>>>(OA, wout, x, out);
}